// Round 4
// baseline (1081.635 us; speedup 1.0000x reference)
//
#include <hip/hip_runtime.h>
#include <stdint.h>

typedef float f4 __attribute__((ext_vector_type(4)));

// phase-rotated (x,y,z) repeating pattern: element at float-position q has
// component (q mod 3); chunk starting at phase t -> {a_t, a_{t+1}, a_{t+2}, a_{t+3 mod 3}}
__device__ __forceinline__ f4 rot3(float x, float y, float z, int t) {
    float a0 = (t == 0) ? x : ((t == 1) ? y : z);
    float a1 = (t == 0) ? y : ((t == 1) ? z : x);
    float a2 = (t == 0) ? z : ((t == 1) ? x : y);
    f4 r = {a0, a1, a2, a0};
    return r;
}

// Substream-major layout: output = 16 substreams of P floats.
//   0: idx_i[0,P)=pi   1: idx_i[P,2P)=pj   2: idx_j[0,P)=pj   3: idx_j[P,2P)=pi
//   4-9: offsets 6P    (first 3P = -shift rows, next 3P = +shift rows)
//   10,11: d2 (both halves identical)   12,13: mask c0   14,15: mask c1
// Each BLOCK serves exactly one substream (blocks_per_sub = (P/16)/256 = 3584),
// each thread writes 16 consecutive floats (4x f4 = 64 B dense). Consecutive
// blocks write consecutive regions of one substream -> at any instant the
// ~2k co-resident blocks form <=2 near-sequential write windows (fill-like),
// instead of ~32k interleaved 1KB windows (round-2's 3.0 TB/s limiter).
__global__ __launch_bounds__(256) void nl_kernel(
    const float* __restrict__ pos,      // (n_ml+n_mm, 3)
    const float* __restrict__ cell,     // (3,3) row-major
    const float* __restrict__ cutoffs,  // (2,)
    const int*   __restrict__ shifts,   // (S,3)
    const int*   __restrict__ ml_idx,   // (n_ml,)
    const int*   __restrict__ mm_idx,   // (n_mm,)
    float* __restrict__ out,            // float32, 16P elements
    int n_mm, int P0, int P, int blocks_per_sub)
{
    int sub = blockIdx.x / blocks_per_sub;               // block-uniform
    int rb  = blockIdx.x - sub * blocks_per_sub;
    int u   = rb * blockDim.x + (int)threadIdx.x;        // thread slot in sub
    int p   = u << 4;                                    // 16 floats per thread
    if (p >= P) return;

    float* dst = out + (size_t)sub * (size_t)P + (size_t)p;

    // ---- shift_vec helper data (uniform scalar loads) ----
    // s is block-uniform: block spans 4096 pairs, image size P0 is a multiple.
    if (sub == 0 || sub == 3) {                          // pi broadcast
        int a = p % P0;
        int pi = ml_idx[a / n_mm];
        float fI = (float)pi;
        f4 v = {fI, fI, fI, fI};
        f4* o = (f4*)dst;
        o[0] = v; o[1] = v; o[2] = v; o[3] = v;
    } else if (sub == 1 || sub == 2) {                   // pj as float
        int a = p % P0;
        int j0 = a % n_mm;                               // 16 | n_mm
        f4* o = (f4*)dst;
#pragma unroll
        for (int g = 0; g < 4; ++g) {
            int4 pj4 = *(const int4*)(mm_idx + j0 + 4 * g);
            f4 v = {(float)pj4.x, (float)pj4.y, (float)pj4.z, (float)pj4.w};
            o[g] = v;
        }
    } else if (sub >= 4 && sub <= 9) {                   // offsets
        // q = float position within the 6P offsets region
        int q = (sub - 4) * P + p;                       // < 6P = 88M, fits int
        int P3 = 3 * P;
        int neg = (q < P3);                              // rows [0,P) are -shift
        int q2 = neg ? q : (q - P3);                     // position in 3P half
        int row = q2 / 3;                                // pair row (uniform image)
        int s = row / P0;
        int sx = 0, sy = 0, sz = 0;
        if (s > 0) {
            sx = shifts[3 * (s - 1) + 0];
            sy = shifts[3 * (s - 1) + 1];
            sz = shifts[3 * (s - 1) + 2];
        }
        float fx = (float)sx, fy = (float)sy, fz = (float)sz;
        float svx = __fadd_rn(__fadd_rn(__fmul_rn(fx, cell[0]), __fmul_rn(fy, cell[3])), __fmul_rn(fz, cell[6]));
        float svy = __fadd_rn(__fadd_rn(__fmul_rn(fx, cell[1]), __fmul_rn(fy, cell[4])), __fmul_rn(fz, cell[7]));
        float svz = __fadd_rn(__fadd_rn(__fmul_rn(fx, cell[2]), __fmul_rn(fy, cell[5])), __fmul_rn(fz, cell[8]));
        if (neg) { svx = -svx; svy = -svy; svz = -svz; }
        int t0 = q2 % 3;
        f4* o = (f4*)dst;
#pragma unroll
        for (int c = 0; c < 4; ++c) {
            int t = (t0 + 4 * c) % 3;
            o[c] = rot3(svx, svy, svz, t);
        }
    } else {                                             // d2 (10,11) / masks (12..15)
        int s = p / P0;
        int a = p - s * P0;
        int i_idx = a / n_mm;
        int j0 = a - i_idx * n_mm;
        int pi = ml_idx[i_idx];
        float xi = pos[3 * pi + 0], yi = pos[3 * pi + 1], zi = pos[3 * pi + 2];
        int sx = 0, sy = 0, sz = 0;
        if (s > 0) {
            sx = shifts[3 * (s - 1) + 0];
            sy = shifts[3 * (s - 1) + 1];
            sz = shifts[3 * (s - 1) + 2];
        }
        float fx = (float)sx, fy = (float)sy, fz = (float)sz;
        float svx = __fadd_rn(__fadd_rn(__fmul_rn(fx, cell[0]), __fmul_rn(fy, cell[3])), __fmul_rn(fz, cell[6]));
        float svy = __fadd_rn(__fadd_rn(__fmul_rn(fx, cell[1]), __fmul_rn(fy, cell[4])), __fmul_rn(fz, cell[7]));
        float svz = __fadd_rn(__fadd_rn(__fmul_rn(fx, cell[2]), __fmul_rn(fy, cell[5])), __fmul_rn(fz, cell[8]));

        bool is_d2 = (sub < 12);
        float cc = (sub < 14) ? __fmul_rn(cutoffs[0], cutoffs[0])
                              : __fmul_rn(cutoffs[1], cutoffs[1]);
        f4* o = (f4*)dst;
#pragma unroll
        for (int g = 0; g < 4; ++g) {
            int4 pj4 = *(const int4*)(mm_idx + j0 + 4 * g);
            int pjs[4] = {pj4.x, pj4.y, pj4.z, pj4.w};
            f4 v;
#pragma unroll
            for (int k = 0; k < 4; ++k) {
                int pj = pjs[k];
                float xj = pos[3 * pj + 0], yj = pos[3 * pj + 1], zj = pos[3 * pj + 2];
                float dx = __fadd_rn(__fsub_rn(xi, xj), svx);
                float dy = __fadd_rn(__fsub_rn(yi, yj), svy);
                float dz = __fadd_rn(__fsub_rn(zi, zj), svz);
                float d2 = __fadd_rn(__fadd_rn(__fmul_rn(dx, dx), __fmul_rn(dy, dy)), __fmul_rn(dz, dz));
                v[k] = is_d2 ? d2 : ((d2 < cc) ? 1.0f : 0.0f);
            }
            o[g] = v;
        }
    }
}

extern "C" void kernel_launch(void* const* d_in, const int* in_sizes, int n_in,
                              void* d_out, int out_size, void* d_ws, size_t ws_size,
                              hipStream_t stream) {
    const float* pos    = (const float*)d_in[0];
    const float* cell   = (const float*)d_in[1];
    const float* cut    = (const float*)d_in[2];
    const int*   shifts = (const int*)d_in[3];
    const int*   ml     = (const int*)d_in[4];
    const int*   mm     = (const int*)d_in[5];

    int n_ml = in_sizes[4];
    int n_mm = in_sizes[5];
    int S    = in_sizes[3] / 3;
    int P0   = n_ml * n_mm;              // 1048576
    int P    = (S + 1) * P0;             // 14,680,064 ; out_size == 16*P

    int threads_per_sub = P / 16;        // 917,504 (each thread: 16 floats)
    int blocks_per_sub  = (threads_per_sub + 255) / 256;   // 3584 exact
    int grid = 16 * blocks_per_sub;      // 57,344
    nl_kernel<<<grid, 256, 0, stream>>>(pos, cell, cut, shifts, ml, mm,
                                        (float*)d_out, n_mm, P0, P, blocks_per_sub);
}

// Round 5
// 948.850 us; speedup vs baseline: 1.1399x; 1.1399x over previous
//
#include <hip/hip_runtime.h>
#include <stdint.h>

typedef float f4 __attribute__((ext_vector_type(4)));

// phase-rotated (x,y,z) pattern: float-position q holds component (q mod 3);
// a 16B chunk starting at phase t -> {a_t, a_{t+1 mod 3}, a_{t+2 mod 3}, a_t}
__device__ __forceinline__ f4 rot3(float x, float y, float z, int t) {
    float a0 = (t == 0) ? x : ((t == 1) ? y : z);
    float a1 = (t == 0) ? y : ((t == 1) ? z : x);
    float a2 = (t == 0) ? z : ((t == 1) ? x : y);
    f4 r = {a0, a1, a2, a0};
    return r;
}

__device__ __forceinline__ void shift_vec(
    const float* __restrict__ cell, const int* __restrict__ shifts, int s,
    float& svx, float& svy, float& svz)
{
    int sx = 0, sy = 0, sz = 0;
    if (s > 0) {
        sx = shifts[3 * (s - 1) + 0];
        sy = shifts[3 * (s - 1) + 1];
        sz = shifts[3 * (s - 1) + 2];
    }
    float fx = (float)sx, fy = (float)sy, fz = (float)sz;
    svx = __fadd_rn(__fadd_rn(__fmul_rn(fx, cell[0]), __fmul_rn(fy, cell[3])), __fmul_rn(fz, cell[6]));
    svy = __fadd_rn(__fadd_rn(__fmul_rn(fx, cell[1]), __fmul_rn(fy, cell[4])), __fmul_rn(fz, cell[7]));
    svz = __fadd_rn(__fadd_rn(__fmul_rn(fx, cell[2]), __fmul_rn(fy, cell[5])), __fmul_rn(fz, cell[8]));
}

// Output = 16 substreams of P floats:
//   0:pi 1:pj 2:pj 3:pi | 4-9: offsets (3P of -shift rows, 3P of +shift) |
//   10,11: d2 x2 | 12,13: mask c0 x2 | 14,15: mask c1 x2
// Three block families (R3 post-mortem: substream-major writes are full-BW,
// but 16-pairs-per-thread gathers x6 recompute were the 320us regression):
//   C [0,nC):        4 pairs/thread, compute d2 ONCE, 6 f4 stores (subs 10-15)
//   A [nC,nC+nA):    4 pairs/thread, int4 mm load, 4 f4 stores (subs 0-3)
//   B [nC+nA,...):   one offsets-substream per block, 16 floats/thread (R3 branch)
__global__ __launch_bounds__(256) void nl_kernel(
    const float* __restrict__ pos,      // (n_ml+n_mm, 3)
    const float* __restrict__ cell,     // (3,3) row-major
    const float* __restrict__ cutoffs,  // (2,)
    const int*   __restrict__ shifts,   // (S,3)
    const int*   __restrict__ ml_idx,   // (n_ml,)
    const int*   __restrict__ mm_idx,   // (n_mm,)
    float* __restrict__ out,            // float32, 16P elements
    int n_mm, int P0, int P, int nC, int nA, int bps16)
{
    size_t Pz = (size_t)P;
    int b = blockIdx.x;

    if (b < nC + nA) {
        // ---- families C and A: 4 consecutive pairs per thread ----
        bool isC = (b < nC);
        int cb = isC ? b : (b - nC);
        int p = (cb << 10) + ((int)threadIdx.x << 2);    // 1024 pairs/block
        if (p >= P) return;
        size_t pp = (size_t)p;

        int s     = p / P0;
        int a     = p - s * P0;
        int i_idx = a / n_mm;
        int j0    = a - i_idx * n_mm;                    // multiple of 4
        int4 pj4  = *(const int4*)(mm_idx + j0);

        if (!isC) {
            // A: idx streams only
            float fI = (float)ml_idx[i_idx];
            f4 vI = {fI, fI, fI, fI};
            f4 vJ = {(float)pj4.x, (float)pj4.y, (float)pj4.z, (float)pj4.w};
            *(f4*)(out + 0 * Pz + pp) = vI;
            *(f4*)(out + 1 * Pz + pp) = vJ;
            *(f4*)(out + 2 * Pz + pp) = vJ;
            *(f4*)(out + 3 * Pz + pp) = vI;
            return;
        }

        // C: d2 + masks, computed once, fanned out to 6 substreams
        int pi = ml_idx[i_idx];
        float xi = pos[3 * pi + 0], yi = pos[3 * pi + 1], zi = pos[3 * pi + 2];
        float svx, svy, svz;
        shift_vec(cell, shifts, s, svx, svy, svz);
        float c0 = __fmul_rn(cutoffs[0], cutoffs[0]);
        float c1 = __fmul_rn(cutoffs[1], cutoffs[1]);

        int pjs[4] = {pj4.x, pj4.y, pj4.z, pj4.w};
        f4 vD, vM0, vM1;
#pragma unroll
        for (int k = 0; k < 4; ++k) {
            int pj = pjs[k];
            float xj = pos[3 * pj + 0], yj = pos[3 * pj + 1], zj = pos[3 * pj + 2];
            float dx = __fadd_rn(__fsub_rn(xi, xj), svx);
            float dy = __fadd_rn(__fsub_rn(yi, yj), svy);
            float dz = __fadd_rn(__fsub_rn(zi, zj), svz);
            float d2 = __fadd_rn(__fadd_rn(__fmul_rn(dx, dx), __fmul_rn(dy, dy)), __fmul_rn(dz, dz));
            vD[k]  = d2;
            vM0[k] = (d2 < c0) ? 1.0f : 0.0f;
            vM1[k] = (d2 < c1) ? 1.0f : 0.0f;
        }
        *(f4*)(out + 10 * Pz + pp) = vD;
        *(f4*)(out + 11 * Pz + pp) = vD;
        *(f4*)(out + 12 * Pz + pp) = vM0;
        *(f4*)(out + 13 * Pz + pp) = vM0;
        *(f4*)(out + 14 * Pz + pp) = vM1;
        *(f4*)(out + 15 * Pz + pp) = vM1;
        return;
    }

    // ---- family B: offsets, one substream per block (R3's proven branch) ----
    int b2  = b - nC - nA;
    int sub = 4 + b2 / bps16;
    int rb  = b2 - (sub - 4) * bps16;
    int p   = (rb * (int)blockDim.x + (int)threadIdx.x) << 4;  // 16 floats/thread
    if (p >= P) return;
    float* dst = out + (size_t)sub * Pz + (size_t)p;

    int q  = (sub - 4) * P + p;          // float position in 6P offsets region
    int P3 = 3 * P;
    int neg = (q < P3);                  // rows [0,P) carry -shift
    int q2 = neg ? q : (q - P3);
    int row = q2 / 3;
    int s = row / P0;
    float svx, svy, svz;
    shift_vec(cell, shifts, s, svx, svy, svz);
    if (neg) { svx = -svx; svy = -svy; svz = -svz; }
    int t0 = q2 % 3;
    f4* o = (f4*)dst;
#pragma unroll
    for (int c = 0; c < 4; ++c) {
        int t = (t0 + 4 * c) % 3;
        o[c] = rot3(svx, svy, svz, t);
    }
}

extern "C" void kernel_launch(void* const* d_in, const int* in_sizes, int n_in,
                              void* d_out, int out_size, void* d_ws, size_t ws_size,
                              hipStream_t stream) {
    const float* pos    = (const float*)d_in[0];
    const float* cell   = (const float*)d_in[1];
    const float* cut    = (const float*)d_in[2];
    const int*   shifts = (const int*)d_in[3];
    const int*   ml     = (const int*)d_in[4];
    const int*   mm     = (const int*)d_in[5];

    int n_ml = in_sizes[4];
    int n_mm = in_sizes[5];
    int S    = in_sizes[3] / 3;
    int P0   = n_ml * n_mm;              // 1048576
    int P    = (S + 1) * P0;             // 14,680,064 ; out_size == 16*P

    int nC    = (P + 1023) >> 10;        // 14336: d2/mask blocks (1024 pairs ea)
    int nA    = nC;                      // 14336: idx blocks
    int bps16 = (P / 16 + 255) / 256;    // 3584: blocks per offsets-substream
    int nB    = 6 * bps16;               // 21504
    int grid  = nC + nA + nB;            // 50176

    nl_kernel<<<grid, 256, 0, stream>>>(pos, cell, cut, shifts, ml, mm,
                                        (float*)d_out, n_mm, P0, P, nC, nA, bps16);
}